// Round 1
// baseline (4900.946 us; speedup 1.0000x reference)
//
#include <hip/hip_runtime.h>
#include <cstddef>

// HSTU forward, fp32 correctness-first implementation.
// B=8, S=1024 (L=1023+1 pad), D=512, NH=8, hd=64, NL=4, MSL=2048.
//
// ws layout: h [8,1024,512] f32 @ 0      (16 MB)
//            z [8,1024,2048] f32 @ 16MB  (64 MB)   (u|q|k|v after silu(h@W1+b1))
//            y [8,1024,512] f32 @ 80MB   (16 MB)
//            t aliases z (z dead after attention)  -> total 96 MB

#define D_MODEL 512
#define S_LEN 1024
#define NHEADS 8

__device__ __forceinline__ float silu_f(float x) {
  return x / (1.f + __expf(-x));
}

// ---------------- embedding + id construction ----------------
__global__ __launch_bounds__(256) void embed_kernel(
    const int* __restrict__ hist_i, const int* __restrict__ hist_c,
    const int* __restrict__ hlen, const int* __restrict__ tgt_i,
    const int* __restrict__ tgt_c, const float* __restrict__ item_emb,
    const float* __restrict__ cate_emb, const float* __restrict__ seg_emb,
    float* __restrict__ h) {
  int bs = blockIdx.x;            // b*1024 + s
  int b = bs >> 10, s = bs & 1023;
  int l = hlen[b];
  int id, cid, sg;
  if (s == l)       { id = tgt_i[b]; cid = tgt_c[b]; sg = 1; }
  else if (s < 1023){ id = hist_i[b * 1023 + s]; cid = hist_c[b * 1023 + s]; sg = 0; }
  else              { id = 0; cid = 0; sg = 0; }   // pad column
  const float* ie = item_emb + (size_t)id * D_MODEL;
  const float* ce = cate_emb + (size_t)cid * D_MODEL;
  const float* se = seg_emb + (size_t)sg * D_MODEL;
  float* hr = h + (size_t)bs * D_MODEL;
  for (int d = threadIdx.x; d < D_MODEL; d += 256)
    hr[d] = ie[d] + ce[d] + se[d];
}

// ---------------- fp32 tiled GEMM: C = epi(A[M,K] @ W[K,N] + bias) ----------
// 64x64 tile / block, 256 threads, 4x4 per thread, K-step 16.
template <int EPI_SILU>
__global__ __launch_bounds__(256) void sgemm_kernel(
    const float* __restrict__ A, const float* __restrict__ W,
    const float* __restrict__ bias, float* __restrict__ C,
    int M, int N, int K) {
  __shared__ float As[16][68];  // [k][m], padded
  __shared__ float Ws[16][68];  // [k][n], padded
  const int tid = threadIdx.x;
  const int m0 = blockIdx.y * 64, n0 = blockIdx.x * 64;
  const int tx = tid & 15, ty = tid >> 4;
  const int ar = tid >> 2, ac = (tid & 3) * 4;   // A-load: 64 rows x 16 cols
  const int wr = tid >> 4, wc = (tid & 15) * 4;  // W-load: 16 rows x 64 cols
  float acc[4][4] = {};
  for (int k0 = 0; k0 < K; k0 += 16) {
    float4 av = *reinterpret_cast<const float4*>(&A[(size_t)(m0 + ar) * K + k0 + ac]);
    float4 wv = *reinterpret_cast<const float4*>(&W[(size_t)(k0 + wr) * N + n0 + wc]);
    As[ac + 0][ar] = av.x;
    As[ac + 1][ar] = av.y;
    As[ac + 2][ar] = av.z;
    As[ac + 3][ar] = av.w;
    *reinterpret_cast<float4*>(&Ws[wr][wc]) = wv;
    __syncthreads();
#pragma unroll
    for (int kk = 0; kk < 16; kk++) {
      const float4 a = *reinterpret_cast<const float4*>(&As[kk][ty * 4]);
      const float4 b = *reinterpret_cast<const float4*>(&Ws[kk][tx * 4]);
      float aa[4] = {a.x, a.y, a.z, a.w};
      float bb4[4] = {b.x, b.y, b.z, b.w};
#pragma unroll
      for (int i = 0; i < 4; i++)
#pragma unroll
        for (int j = 0; j < 4; j++) acc[i][j] += aa[i] * bb4[j];
    }
    __syncthreads();
  }
#pragma unroll
  for (int i = 0; i < 4; i++) {
    const int m = m0 + ty * 4 + i;
    const int n = n0 + tx * 4;
    float4 c4;
    float* cp = &c4.x;
#pragma unroll
    for (int j = 0; j < 4; j++) {
      float c = acc[i][j] + bias[n + j];
      if (EPI_SILU) c = silu_f(c);
      cp[j] = c;
    }
    *reinterpret_cast<float4*>(&C[(size_t)m * N + n]) = c4;
  }
}

// ---------------- fused causal silu-attention ----------------
// att = silu(q k^T + posw[2047+t-s]) * (t<=s);  y = (att @ v) * u
// z row layout: [u(512) | q(512) | k(512) | v(512)], per-head 64-dim slices.
// Block: one (b, head, 32-row q tile). 256 threads.
__global__ __launch_bounds__(256) void attn_kernel(
    const float* __restrict__ z, const float* __restrict__ posw,
    float* __restrict__ y) {
  const int qt = blockIdx.x, hh = blockIdx.y, b = blockIdx.z;
  const int s0 = qt * 32;
  __shared__ float qs[32][68];
  __shared__ float ks[32][68];
  __shared__ float vs[32][68];
  __shared__ float sc[32][33];
  const float* zb = z + (size_t)b * S_LEN * 2048;
  const int tid = threadIdx.x;
  const int r = tid >> 3;          // q row in tile (0..31)
  const int d0 = (tid & 7) * 8;    // head-dim slice (8 floats)
  const int s = s0 + r;
  const int c0 = (tid & 7) * 4;    // score cols (4 per thread)
  {
    const float* src = zb + (size_t)s * 2048 + 512 + hh * 64 + d0;
    *reinterpret_cast<float4*>(&qs[r][d0])     = *reinterpret_cast<const float4*>(src);
    *reinterpret_cast<float4*>(&qs[r][d0 + 4]) = *reinterpret_cast<const float4*>(src + 4);
  }
  float acc[8] = {};
  for (int kt = 0; kt <= qt; kt++) {
    const int t0 = kt * 32;
    __syncthreads();   // prev iter done with ks/vs/sc; qs visible after next sync
    {
      const float* kp = zb + (size_t)(t0 + r) * 2048 + 1024 + hh * 64 + d0;
      const float* vp = zb + (size_t)(t0 + r) * 2048 + 1536 + hh * 64 + d0;
      *reinterpret_cast<float4*>(&ks[r][d0])     = *reinterpret_cast<const float4*>(kp);
      *reinterpret_cast<float4*>(&ks[r][d0 + 4]) = *reinterpret_cast<const float4*>(kp + 4);
      *reinterpret_cast<float4*>(&vs[r][d0])     = *reinterpret_cast<const float4*>(vp);
      *reinterpret_cast<float4*>(&vs[r][d0 + 4]) = *reinterpret_cast<const float4*>(vp + 4);
    }
    __syncthreads();
    float dots[4] = {};
#pragma unroll
    for (int kk = 0; kk < 16; kk++) {
      const float4 qv = *reinterpret_cast<const float4*>(&qs[r][kk * 4]);
#pragma unroll
      for (int c = 0; c < 4; c++) {
        const float4 kv = *reinterpret_cast<const float4*>(&ks[c0 + c][kk * 4]);
        dots[c] += qv.x * kv.x + qv.y * kv.y + qv.z * kv.z + qv.w * kv.w;
      }
    }
#pragma unroll
    for (int c = 0; c < 4; c++) {
      const int t = t0 + c0 + c;
      const float x = dots[c] + posw[2047 + t - s];
      sc[r][c0 + c] = (t <= s) ? silu_f(x) : 0.f;
    }
    __syncthreads();
#pragma unroll
    for (int t = 0; t < 32; t++) {
      const float a = sc[r][t];
      const float4 v0 = *reinterpret_cast<const float4*>(&vs[t][d0]);
      const float4 v1 = *reinterpret_cast<const float4*>(&vs[t][d0 + 4]);
      acc[0] += a * v0.x; acc[1] += a * v0.y; acc[2] += a * v0.z; acc[3] += a * v0.w;
      acc[4] += a * v1.x; acc[5] += a * v1.y; acc[6] += a * v1.z; acc[7] += a * v1.w;
    }
  }
  const float* up = zb + (size_t)s * 2048 + hh * 64 + d0;   // u gate
  float* yp = y + ((size_t)(b * S_LEN + s)) * D_MODEL + hh * 64 + d0;
#pragma unroll
  for (int j = 0; j < 8; j++) yp[j] = acc[j] * up[j];
}

// ---------------- layer norm (optional fused residual) ----------------
// o[row] = LN(x[row] (+ res[row])) * w + b.  One block per row; in-place safe
// (all reads precede the reduction barrier, writes follow it).
__global__ __launch_bounds__(256) void ln_kernel(
    const float* __restrict__ x, const float* __restrict__ res,
    const float* __restrict__ w, const float* __restrict__ bb,
    float* __restrict__ o) {
  const size_t row = blockIdx.x;
  const int i0 = threadIdx.x, i1 = threadIdx.x + 256;
  float v0 = x[row * D_MODEL + i0];
  float v1 = x[row * D_MODEL + i1];
  if (res) {
    v0 += res[row * D_MODEL + i0];
    v1 += res[row * D_MODEL + i1];
  }
  float s = v0 + v1, ss = v0 * v0 + v1 * v1;
#pragma unroll
  for (int off = 32; off; off >>= 1) {
    s += __shfl_down(s, off, 64);
    ss += __shfl_down(ss, off, 64);
  }
  __shared__ float sbuf[4], ssbuf[4];
  __shared__ float mu_s, rstd_s;
  const int wid = threadIdx.x >> 6, lane = threadIdx.x & 63;
  if (lane == 0) { sbuf[wid] = s; ssbuf[wid] = ss; }
  __syncthreads();
  if (threadIdx.x == 0) {
    const float S = sbuf[0] + sbuf[1] + sbuf[2] + sbuf[3];
    const float SS = ssbuf[0] + ssbuf[1] + ssbuf[2] + ssbuf[3];
    const float mu = S * (1.f / D_MODEL);
    const float var = SS * (1.f / D_MODEL) - mu * mu;
    mu_s = mu;
    rstd_s = rsqrtf(var + 1e-5f);
  }
  __syncthreads();
  const float mu = mu_s, rstd = rstd_s;
  o[row * D_MODEL + i0] = (v0 - mu) * rstd * w[i0] + bb[i0];
  o[row * D_MODEL + i1] = (v1 - mu) * rstd * w[i1] + bb[i1];
}

extern "C" void kernel_launch(void* const* d_in, const int* in_sizes, int n_in,
                              void* d_out, int out_size, void* d_ws, size_t ws_size,
                              hipStream_t stream) {
  const int* hist_i = (const int*)d_in[0];
  const int* hist_c = (const int*)d_in[1];
  const int* hlen   = (const int*)d_in[2];
  const int* tgt_i  = (const int*)d_in[3];
  const int* tgt_c  = (const int*)d_in[4];
  const float* item_emb = (const float*)d_in[5];
  const float* cate_emb = (const float*)d_in[6];
  const float* seg_emb  = (const float*)d_in[7];
  const float* W1   = (const float*)d_in[8];    // [4,512,2048]
  const float* b1   = (const float*)d_in[9];    // [4,2048]
  const float* W2   = (const float*)d_in[10];   // [4,512,512]
  const float* b2   = (const float*)d_in[11];   // [4,512]
  const float* ln1w = (const float*)d_in[12];
  const float* ln1b = (const float*)d_in[13];
  const float* ln2w = (const float*)d_in[14];
  const float* ln2b = (const float*)d_in[15];
  const float* posw = (const float*)d_in[16];   // [4,4095]
  const float* lnfw = (const float*)d_in[17];
  const float* lnfb = (const float*)d_in[18];
  float* out = (float*)d_out;

  char* ws = (char*)d_ws;
  float* h = (float*)ws;                           // 16 MB
  float* z = (float*)(ws + (16u << 20));           // 64 MB
  float* y = (float*)(ws + (80u << 20));           // 16 MB
  float* t = z;                                    // z dead after attention

  const int ROWS = 8 * S_LEN;  // 8192

  embed_kernel<<<ROWS, 256, 0, stream>>>(hist_i, hist_c, hlen, tgt_i, tgt_c,
                                         item_emb, cate_emb, seg_emb, h);
  for (int l = 0; l < 4; l++) {
    // z = silu(h @ W1[l] + b1[l])   [8192, 2048]
    sgemm_kernel<1><<<dim3(2048 / 64, ROWS / 64), 256, 0, stream>>>(
        h, W1 + (size_t)l * 512 * 2048, b1 + (size_t)l * 2048, z, ROWS, 2048, 512);
    // y = (silu-att @ v) * u        [8192, 512]
    attn_kernel<<<dim3(S_LEN / 32, NHEADS, 8), 256, 0, stream>>>(
        z, posw + (size_t)l * 4095, y);
    // y = LN1(y)  (in place)
    ln_kernel<<<ROWS, 256, 0, stream>>>(y, nullptr, ln1w + l * 512, ln1b + l * 512, y);
    // t = y @ W2[l] + b2[l]
    sgemm_kernel<0><<<dim3(512 / 64, ROWS / 64), 256, 0, stream>>>(
        y, W2 + (size_t)l * 512 * 512, b2 + (size_t)l * 512, t, ROWS, 512, 512);
    // h = LN2(t + h)  (in place on h)
    ln_kernel<<<ROWS, 256, 0, stream>>>(t, h, ln2w + l * 512, ln2b + l * 512, h);
  }
  // out = LNf(h)
  ln_kernel<<<ROWS, 256, 0, stream>>>(h, nullptr, lnfw, lnfb, out);
}

// Round 2
// 1992.384 us; speedup vs baseline: 2.4598x; 2.4598x over previous
//
#include <hip/hip_runtime.h>
#include <cstddef>

// HSTU forward. Round 2: MFMA bf16 fused attention; fp32 GEMMs/LN unchanged.
// B=8, S=1024, D=512, NH=8, hd=64, NL=4, MSL=2048.
//
// ws layout: h [8,1024,512] f32 @ 0      (16 MB)
//            z [8,1024,2048] f32 @ 16MB  (64 MB)   (u|q|k|v after silu(h@W1+b1))
//            y [8,1024,512] f32 @ 80MB   (16 MB)
//            t aliases z (z dead after attention)  -> total 96 MB

#define D_MODEL 512
#define S_LEN 1024
#define NHEADS 8

typedef __bf16 bf16x8 __attribute__((ext_vector_type(8)));
typedef float f32x4 __attribute__((ext_vector_type(4)));
typedef unsigned short us4 __attribute__((ext_vector_type(4)));

__device__ __forceinline__ float silu_f(float x) {
  return x / (1.f + __expf(-x));
}

__device__ __forceinline__ unsigned short f2bf(float f) {
  unsigned int u = __float_as_uint(f);
  u += 0x7FFF + ((u >> 16) & 1);   // round-to-nearest-even
  return (unsigned short)(u >> 16);
}

// ---------------- embedding + id construction ----------------
__global__ __launch_bounds__(256) void embed_kernel(
    const int* __restrict__ hist_i, const int* __restrict__ hist_c,
    const int* __restrict__ hlen, const int* __restrict__ tgt_i,
    const int* __restrict__ tgt_c, const float* __restrict__ item_emb,
    const float* __restrict__ cate_emb, const float* __restrict__ seg_emb,
    float* __restrict__ h) {
  int bs = blockIdx.x;            // b*1024 + s
  int b = bs >> 10, s = bs & 1023;
  int l = hlen[b];
  int id, cid, sg;
  if (s == l)       { id = tgt_i[b]; cid = tgt_c[b]; sg = 1; }
  else if (s < 1023){ id = hist_i[b * 1023 + s]; cid = hist_c[b * 1023 + s]; sg = 0; }
  else              { id = 0; cid = 0; sg = 0; }   // pad column
  const float* ie = item_emb + (size_t)id * D_MODEL;
  const float* ce = cate_emb + (size_t)cid * D_MODEL;
  const float* se = seg_emb + (size_t)sg * D_MODEL;
  float* hr = h + (size_t)bs * D_MODEL;
  for (int d = threadIdx.x; d < D_MODEL; d += 256)
    hr[d] = ie[d] + ce[d] + se[d];
}

// ---------------- fp32 tiled GEMM: C = epi(A[M,K] @ W[K,N] + bias) ----------
template <int EPI_SILU>
__global__ __launch_bounds__(256) void sgemm_kernel(
    const float* __restrict__ A, const float* __restrict__ W,
    const float* __restrict__ bias, float* __restrict__ C,
    int M, int N, int K) {
  __shared__ float As[16][68];  // [k][m], padded
  __shared__ float Ws[16][68];  // [k][n], padded
  const int tid = threadIdx.x;
  const int m0 = blockIdx.y * 64, n0 = blockIdx.x * 64;
  const int tx = tid & 15, ty = tid >> 4;
  const int ar = tid >> 2, ac = (tid & 3) * 4;   // A-load: 64 rows x 16 cols
  const int wr = tid >> 4, wc = (tid & 15) * 4;  // W-load: 16 rows x 64 cols
  float acc[4][4] = {};
  for (int k0 = 0; k0 < K; k0 += 16) {
    float4 av = *reinterpret_cast<const float4*>(&A[(size_t)(m0 + ar) * K + k0 + ac]);
    float4 wv = *reinterpret_cast<const float4*>(&W[(size_t)(k0 + wr) * N + n0 + wc]);
    As[ac + 0][ar] = av.x;
    As[ac + 1][ar] = av.y;
    As[ac + 2][ar] = av.z;
    As[ac + 3][ar] = av.w;
    *reinterpret_cast<float4*>(&Ws[wr][wc]) = wv;
    __syncthreads();
#pragma unroll
    for (int kk = 0; kk < 16; kk++) {
      const float4 a = *reinterpret_cast<const float4*>(&As[kk][ty * 4]);
      const float4 b = *reinterpret_cast<const float4*>(&Ws[kk][tx * 4]);
      float aa[4] = {a.x, a.y, a.z, a.w};
      float bb4[4] = {b.x, b.y, b.z, b.w};
#pragma unroll
      for (int i = 0; i < 4; i++)
#pragma unroll
        for (int j = 0; j < 4; j++) acc[i][j] += aa[i] * bb4[j];
    }
    __syncthreads();
  }
#pragma unroll
  for (int i = 0; i < 4; i++) {
    const int m = m0 + ty * 4 + i;
    const int n = n0 + tx * 4;
    float4 c4;
    float* cp = &c4.x;
#pragma unroll
    for (int j = 0; j < 4; j++) {
      float c = acc[i][j] + bias[n + j];
      if (EPI_SILU) c = silu_f(c);
      cp[j] = c;
    }
    *reinterpret_cast<float4*>(&C[(size_t)m * N + n]) = c4;
  }
}

// ---------------- fused causal silu-attention, MFMA bf16 ----------------
// att = silu(q k^T + posw[2047+t-s]) * (t<=s);  y = (att @ v) * u
// z row layout: [u(512) | q(512) | k(512) | v(512)], per-head 64-dim slices.
// Block: one (b, head, 64-row q tile). 256 threads = 4 waves; wave w owns
// q rows [w*16, w*16+16). mfma_f32_16x16x32_bf16 layouts (m89-verified):
//   A/B frag: [lane&15][ (lane>>4)*8 + j ],  C/D: col=lane&15, row=quad*4+reg.
// Vt is V transposed ([d][t]) with t-block-xor swizzle so both the staging
// ds_write_b64 and the B-fragment ds_read_b128 are conflict-free.
#define LDR 72   // LDS row stride in u16 (144 B, 16B-aligned, bank-spread)
__global__ __launch_bounds__(256) void attn_kernel(
    const float* __restrict__ z, const float* __restrict__ posw,
    float* __restrict__ y) {
  const int qt = blockIdx.x, hh = blockIdx.y, b = blockIdx.z;
  const int s0 = qt * 64;
  __shared__ alignas(16) unsigned short Qs[64 * LDR];
  __shared__ alignas(16) unsigned short Ks[64 * LDR];
  __shared__ alignas(16) unsigned short Vt[64 * LDR];
  __shared__ alignas(16) unsigned short Ps[64 * LDR];
  const float* zb = z + (size_t)b * S_LEN * 2048;
  const int tid = threadIdx.x;
  const int w = tid >> 6, lane = tid & 63, lm = lane & 15, quad = lane >> 4;

  // ---- stage Q tile (64 x 64) as bf16 ----
  {
    const int col = (tid & 15) * 4;
#pragma unroll
    for (int p = 0; p < 4; p++) {
      const int r = (tid >> 4) + p * 16;
      const float4 v = *reinterpret_cast<const float4*>(
          zb + (size_t)(s0 + r) * 2048 + 512 + hh * 64 + col);
      us4 o = { f2bf(v.x), f2bf(v.y), f2bf(v.z), f2bf(v.w) };
      *reinterpret_cast<us4*>(&Qs[r * LDR + col]) = o;
    }
  }

  f32x4 O[4] = {};   // output accumulator, C-layout, 16 rows x 64 d per wave

  for (int kt = 0; kt <= qt; kt++) {
    const int t0 = kt * 64;
    __syncthreads();   // prev iteration's readers of Ks/Vt are done
    // ---- stage K tile (64 x 64) ----
    {
      const int col = (tid & 15) * 4;
#pragma unroll
      for (int p = 0; p < 4; p++) {
        const int r = (tid >> 4) + p * 16;
        const float4 v = *reinterpret_cast<const float4*>(
            zb + (size_t)(t0 + r) * 2048 + 1024 + hh * 64 + col);
        us4 o = { f2bf(v.x), f2bf(v.y), f2bf(v.z), f2bf(v.w) };
        *reinterpret_cast<us4*>(&Ks[r * LDR + col]) = o;
      }
    }
    // ---- stage V transposed + swizzled: Vt[d][(tb ^ (d&7))*8 + ti] ----
    {
      const int t = (tid >> 4) * 4;      // 0..60
      const int d = (tid & 15) * 4;      // 0..60
      float c[4][4];
#pragma unroll
      for (int r = 0; r < 4; r++) {
        const float4 v = *reinterpret_cast<const float4*>(
            zb + (size_t)(t0 + t + r) * 2048 + 1536 + hh * 64 + d);
        c[r][0] = v.x; c[r][1] = v.y; c[r][2] = v.z; c[r][3] = v.w;
      }
      const int tb = t >> 3, ti = t & 7;
#pragma unroll
      for (int j = 0; j < 4; j++) {
        const int dd = d + j;
        us4 o = { f2bf(c[0][j]), f2bf(c[1][j]), f2bf(c[2][j]), f2bf(c[3][j]) };
        *reinterpret_cast<us4*>(&Vt[dd * LDR + ((tb ^ (dd & 7)) << 3) + ti]) = o;
      }
    }
    __syncthreads();   // staging visible to all waves

    // ---- S = Q K^T (16x64 stripe per wave) ----
    const bf16x8 qa0 = *reinterpret_cast<const bf16x8*>(&Qs[(w * 16 + lm) * LDR + quad * 8]);
    const bf16x8 qa1 = *reinterpret_cast<const bf16x8*>(&Qs[(w * 16 + lm) * LDR + 32 + quad * 8]);
    f32x4 S[4];
#pragma unroll
    for (int ct = 0; ct < 4; ct++) {
      const bf16x8 kb0 = *reinterpret_cast<const bf16x8*>(&Ks[(ct * 16 + lm) * LDR + quad * 8]);
      const bf16x8 kb1 = *reinterpret_cast<const bf16x8*>(&Ks[(ct * 16 + lm) * LDR + 32 + quad * 8]);
      f32x4 acc = {};
      acc = __builtin_amdgcn_mfma_f32_16x16x32_bf16(qa0, kb0, acc, 0, 0, 0);
      acc = __builtin_amdgcn_mfma_f32_16x16x32_bf16(qa1, kb1, acc, 0, 0, 0);
      S[ct] = acc;
    }

    // ---- bias + silu + causal mask -> Ps (wave-private stripe, no barrier) --
    {
      const int srow = s0 + w * 16 + quad * 4;
#pragma unroll
      for (int ct = 0; ct < 4; ct++) {
#pragma unroll
        for (int i = 0; i < 4; i++) {
          const int sg = srow + i;
          const int t = t0 + ct * 16 + lm;
          const float x = S[ct][i] + posw[2047 + t - sg];
          const float val = (t <= sg) ? silu_f(x) : 0.f;
          Ps[(w * 16 + quad * 4 + i) * LDR + ct * 16 + lm] = f2bf(val);
        }
      }
    }

    // ---- O += P V (reads own Ps stripe + Vt) ----
    const bf16x8 pa0 = *reinterpret_cast<const bf16x8*>(&Ps[(w * 16 + lm) * LDR + quad * 8]);
    const bf16x8 pa1 = *reinterpret_cast<const bf16x8*>(&Ps[(w * 16 + lm) * LDR + 32 + quad * 8]);
#pragma unroll
    for (int ct = 0; ct < 4; ct++) {
      const int d = ct * 16 + lm;
      const bf16x8 vb0 = *reinterpret_cast<const bf16x8*>(
          &Vt[d * LDR + ((quad ^ (d & 7)) << 3)]);            // k-step 0: tb=quad
      const bf16x8 vb1 = *reinterpret_cast<const bf16x8*>(
          &Vt[d * LDR + (((4 + quad) ^ (d & 7)) << 3)]);      // k-step 1: tb=4+quad
      O[ct] = __builtin_amdgcn_mfma_f32_16x16x32_bf16(pa0, vb0, O[ct], 0, 0, 0);
      O[ct] = __builtin_amdgcn_mfma_f32_16x16x32_bf16(pa1, vb1, O[ct], 0, 0, 0);
    }
  }

  // ---- epilogue: y = O * u ----
  {
    const int srow = s0 + w * 16 + quad * 4;
#pragma unroll
    for (int ct = 0; ct < 4; ct++) {
      const int d = ct * 16 + lm;
#pragma unroll
      for (int i = 0; i < 4; i++) {
        const int sg = srow + i;
        const float u = zb[(size_t)sg * 2048 + hh * 64 + d];
        y[((size_t)(b * S_LEN + sg)) * D_MODEL + hh * 64 + d] = O[ct][i] * u;
      }
    }
  }
}

// ---------------- layer norm (optional fused residual) ----------------
__global__ __launch_bounds__(256) void ln_kernel(
    const float* __restrict__ x, const float* __restrict__ res,
    const float* __restrict__ w, const float* __restrict__ bb,
    float* __restrict__ o) {
  const size_t row = blockIdx.x;
  const int i0 = threadIdx.x, i1 = threadIdx.x + 256;
  float v0 = x[row * D_MODEL + i0];
  float v1 = x[row * D_MODEL + i1];
  if (res) {
    v0 += res[row * D_MODEL + i0];
    v1 += res[row * D_MODEL + i1];
  }
  float s = v0 + v1, ss = v0 * v0 + v1 * v1;
#pragma unroll
  for (int off = 32; off; off >>= 1) {
    s += __shfl_down(s, off, 64);
    ss += __shfl_down(ss, off, 64);
  }
  __shared__ float sbuf[4], ssbuf[4];
  __shared__ float mu_s, rstd_s;
  const int wid = threadIdx.x >> 6, lane = threadIdx.x & 63;
  if (lane == 0) { sbuf[wid] = s; ssbuf[wid] = ss; }
  __syncthreads();
  if (threadIdx.x == 0) {
    const float S = sbuf[0] + sbuf[1] + sbuf[2] + sbuf[3];
    const float SS = ssbuf[0] + ssbuf[1] + ssbuf[2] + ssbuf[3];
    const float mu = S * (1.f / D_MODEL);
    const float var = SS * (1.f / D_MODEL) - mu * mu;
    mu_s = mu;
    rstd_s = rsqrtf(var + 1e-5f);
  }
  __syncthreads();
  const float mu = mu_s, rstd = rstd_s;
  o[row * D_MODEL + i0] = (v0 - mu) * rstd * w[i0] + bb[i0];
  o[row * D_MODEL + i1] = (v1 - mu) * rstd * w[i1] + bb[i1];
}

extern "C" void kernel_launch(void* const* d_in, const int* in_sizes, int n_in,
                              void* d_out, int out_size, void* d_ws, size_t ws_size,
                              hipStream_t stream) {
  const int* hist_i = (const int*)d_in[0];
  const int* hist_c = (const int*)d_in[1];
  const int* hlen   = (const int*)d_in[2];
  const int* tgt_i  = (const int*)d_in[3];
  const int* tgt_c  = (const int*)d_in[4];
  const float* item_emb = (const float*)d_in[5];
  const float* cate_emb = (const float*)d_in[6];
  const float* seg_emb  = (const float*)d_in[7];
  const float* W1   = (const float*)d_in[8];    // [4,512,2048]
  const float* b1   = (const float*)d_in[9];    // [4,2048]
  const float* W2   = (const float*)d_in[10];   // [4,512,512]
  const float* b2   = (const float*)d_in[11];   // [4,512]
  const float* ln1w = (const float*)d_in[12];
  const float* ln1b = (const float*)d_in[13];
  const float* ln2w = (const float*)d_in[14];
  const float* ln2b = (const float*)d_in[15];
  const float* posw = (const float*)d_in[16];   // [4,4095]
  const float* lnfw = (const float*)d_in[17];
  const float* lnfb = (const float*)d_in[18];
  float* out = (float*)d_out;

  char* ws = (char*)d_ws;
  float* h = (float*)ws;                           // 16 MB
  float* z = (float*)(ws + (16u << 20));           // 64 MB
  float* y = (float*)(ws + (80u << 20));           // 16 MB
  float* t = z;                                    // z dead after attention

  const int ROWS = 8 * S_LEN;  // 8192

  embed_kernel<<<ROWS, 256, 0, stream>>>(hist_i, hist_c, hlen, tgt_i, tgt_c,
                                         item_emb, cate_emb, seg_emb, h);
  for (int l = 0; l < 4; l++) {
    // z = silu(h @ W1[l] + b1[l])   [8192, 2048]
    sgemm_kernel<1><<<dim3(2048 / 64, ROWS / 64), 256, 0, stream>>>(
        h, W1 + (size_t)l * 512 * 2048, b1 + (size_t)l * 2048, z, ROWS, 2048, 512);
    // y = (silu-att @ v) * u        [8192, 512]
    attn_kernel<<<dim3(S_LEN / 64, NHEADS, 8), 256, 0, stream>>>(
        z, posw + (size_t)l * 4095, y);
    // y = LN1(y)  (in place)
    ln_kernel<<<ROWS, 256, 0, stream>>>(y, nullptr, ln1w + l * 512, ln1b + l * 512, y);
    // t = y @ W2[l] + b2[l]
    sgemm_kernel<0><<<dim3(512 / 64, ROWS / 64), 256, 0, stream>>>(
        y, W2 + (size_t)l * 512 * 512, b2 + (size_t)l * 512, t, ROWS, 512, 512);
    // h = LN2(t + h)  (in place on h)
    ln_kernel<<<ROWS, 256, 0, stream>>>(t, h, ln2w + l * 512, ln2b + l * 512, h);
  }
  // out = LNf(h)
  ln_kernel<<<ROWS, 256, 0, stream>>>(h, nullptr, lnfw, lnfb, out);
}

// Round 3
// 967.945 us; speedup vs baseline: 5.0632x; 2.0584x over previous
//
#include <hip/hip_runtime.h>
#include <cstddef>

// HSTU forward. Round 3: bf16 MFMA GEMMs (m97 structure) + bf16 activation
// stream; fp32 residuals/LN. B=8, S=1024, D=512, NH=8, hd=64, NL=4, MSL=2048.
//
// ws layout (90 MB):
//   h32  f32  [8192,512]   @ 0      16 MB   residual stream
//   hbf  bf16 [8192,512]   @ 16 MB   8 MB   GEMM1 A input
//   zbf  bf16 [8192,2048]  @ 24 MB  32 MB   u|q|k|v (GEMM1 out, attn in)
//   ybf  bf16 [8192,512]   @ 56 MB   8 MB   LN1 out (GEMM2 A input)
//   yat  f32  [8192,512]   @ 64 MB  16 MB   attn out; ALIASED by t32 (GEMM2 out)
//   W1t  bf16 [4,2048,512] @ 80 MB   8 MB   transposed bf16 weights
//   W2t  bf16 [4,512,512]  @ 88 MB   2 MB

#define D_MODEL 512
#define S_LEN 1024
#define NHEADS 8

typedef __bf16 bf16x8 __attribute__((ext_vector_type(8)));
typedef float f32x4 __attribute__((ext_vector_type(4)));
typedef unsigned short us4 __attribute__((ext_vector_type(4)));
typedef unsigned short us8 __attribute__((ext_vector_type(8)));

__device__ __forceinline__ float silu_f(float x) {
  return x / (1.f + __expf(-x));
}
__device__ __forceinline__ unsigned short f2bf(float f) {
  unsigned int u = __float_as_uint(f);
  u += 0x7FFF + ((u >> 16) & 1);   // round-to-nearest-even
  return (unsigned short)(u >> 16);
}
__device__ __forceinline__ float bf2f(unsigned short s) {
  return __uint_as_float(((unsigned int)s) << 16);
}
__device__ __forceinline__ void gll16(const void* g, void* l) {
  __builtin_amdgcn_global_load_lds(
      (const __attribute__((address_space(1))) unsigned int*)g,
      (__attribute__((address_space(3))) unsigned int*)l, 16, 0, 0);
}

// ---------------- embedding + id construction (dual f32/bf16 write) --------
__global__ __launch_bounds__(256) void embed_kernel(
    const int* __restrict__ hist_i, const int* __restrict__ hist_c,
    const int* __restrict__ hlen, const int* __restrict__ tgt_i,
    const int* __restrict__ tgt_c, const float* __restrict__ item_emb,
    const float* __restrict__ cate_emb, const float* __restrict__ seg_emb,
    float* __restrict__ h32, unsigned short* __restrict__ hbf) {
  int bs = blockIdx.x;            // b*1024 + s
  int b = bs >> 10, s = bs & 1023;
  int l = hlen[b];
  int id, cid, sg;
  if (s == l)       { id = tgt_i[b]; cid = tgt_c[b]; sg = 1; }
  else if (s < 1023){ id = hist_i[b * 1023 + s]; cid = hist_c[b * 1023 + s]; sg = 0; }
  else              { id = 0; cid = 0; sg = 0; }   // pad column
  const float* ie = item_emb + (size_t)id * D_MODEL;
  const float* ce = cate_emb + (size_t)cid * D_MODEL;
  const float* se = seg_emb + (size_t)sg * D_MODEL;
  float* hr = h32 + (size_t)bs * D_MODEL;
  unsigned short* hb = hbf + (size_t)bs * D_MODEL;
  for (int d = threadIdx.x; d < D_MODEL; d += 256) {
    float v = ie[d] + ce[d] + se[d];
    hr[d] = v;
    hb[d] = f2bf(v);
  }
}

// ---------------- weight transpose + fp32->bf16: Wt[n][k] = W[k][n] --------
__global__ __launch_bounds__(256) void transpose_kernel(
    const float* __restrict__ W, unsigned short* __restrict__ Wt,
    int K, int N) {
  const int l = blockIdx.z;
  W += (size_t)l * K * N;
  Wt += (size_t)l * K * N;
  const int n0 = blockIdx.x * 64, k0 = blockIdx.y * 64;
  __shared__ float T[64][65];
  const int tid = threadIdx.x;
  const int rr = tid >> 4, cc = (tid & 15) * 4;
#pragma unroll
  for (int p = 0; p < 4; p++) {
    const int r = rr + p * 16;
    const float4 v = *reinterpret_cast<const float4*>(&W[(size_t)(k0 + r) * N + n0 + cc]);
    T[r][cc] = v.x; T[r][cc + 1] = v.y; T[r][cc + 2] = v.z; T[r][cc + 3] = v.w;
  }
  __syncthreads();
#pragma unroll
  for (int p = 0; p < 4; p++) {
    const int r = rr + p * 16;       // n within tile
    us4 o = { f2bf(T[cc + 0][r]), f2bf(T[cc + 1][r]),
              f2bf(T[cc + 2][r]), f2bf(T[cc + 3][r]) };
    *reinterpret_cast<us4*>(&Wt[(size_t)(n0 + r) * K + k0 + cc]) = o;
  }
}

// ---------------- bf16 MFMA GEMM: C = epi(A[M,K] @ Bt[N,K]^T + bias) -------
// 128x128 tile, BK=64, 256 threads = 4 waves (2x2), wave tile 64x64.
// LDS: As/Bs [128 rows][64 cols] bf16, xor-swizzled 8-elem chunks:
//   physical chunk p at row r holds logical chunk p ^ (r&7).
// Staged with global_load_lds width=16 (lane-linear LDS dest).
template <int EPI_SILU, typename OutT>
__global__ __launch_bounds__(256) void mfma_gemm(
    const unsigned short* __restrict__ A, const unsigned short* __restrict__ Bt,
    const float* __restrict__ bias, OutT* __restrict__ C,
    int M, int N, int K) {
  __shared__ unsigned short As[128 * 64];
  __shared__ unsigned short Bs[128 * 64];
  const int tid = threadIdx.x;
  const int w = tid >> 6, lane = tid & 63, lm = lane & 15, quad = lane >> 4;
  const int wm = w & 1, wn = w >> 1;
  const int m0 = blockIdx.y * 128, n0 = blockIdx.x * 128;

  f32x4 acc[4][4] = {};

  for (int k0 = 0; k0 < K; k0 += 64) {
    // ---- stage A,B tiles (16 KB each) via global_load_lds ----
#pragma unroll
    for (int p = 0; p < 4; p++) {
      const int g = p * 256 + tid;         // 16B chunk id, 0..1023
      const int r = g >> 3;                // tile row
      const int lc = (g & 7) ^ (r & 7);    // logical k-chunk for this phys slot
      gll16(A + (size_t)(m0 + r) * K + k0 + lc * 8, &As[g * 8]);
      gll16(Bt + (size_t)(n0 + r) * K + k0 + lc * 8, &Bs[g * 8]);
    }
    __syncthreads();
    // ---- compute: 2 k-halves of 32 ----
#pragma unroll
    for (int ki = 0; ki < 2; ki++) {
      bf16x8 af[4], bfr[4];
#pragma unroll
      for (int mi = 0; mi < 4; mi++) {
        const int r = wm * 64 + mi * 16 + lm;
        const int p = (ki * 4 + quad) ^ (lm & 7);
        af[mi] = *reinterpret_cast<const bf16x8*>(&As[r * 64 + p * 8]);
      }
#pragma unroll
      for (int ni = 0; ni < 4; ni++) {
        const int r = wn * 64 + ni * 16 + lm;
        const int p = (ki * 4 + quad) ^ (lm & 7);
        bfr[ni] = *reinterpret_cast<const bf16x8*>(&Bs[r * 64 + p * 8]);
      }
#pragma unroll
      for (int mi = 0; mi < 4; mi++)
#pragma unroll
        for (int ni = 0; ni < 4; ni++)
          acc[mi][ni] = __builtin_amdgcn_mfma_f32_16x16x32_bf16(
              af[mi], bfr[ni], acc[mi][ni], 0, 0, 0);
    }
    __syncthreads();
  }

  // ---- epilogue: bias (+silu), C-layout col=lm, row=quad*4+reg ----
#pragma unroll
  for (int ni = 0; ni < 4; ni++) {
    const int n = n0 + wn * 64 + ni * 16 + lm;
    const float bv = bias[n];
#pragma unroll
    for (int mi = 0; mi < 4; mi++) {
      const int mbase = m0 + wm * 64 + mi * 16 + quad * 4;
#pragma unroll
      for (int reg = 0; reg < 4; reg++) {
        float v = acc[mi][ni][reg] + bv;
        if (EPI_SILU) v = silu_f(v);
        if constexpr (sizeof(OutT) == 2)
          C[(size_t)(mbase + reg) * N + n] = f2bf(v);
        else
          C[(size_t)(mbase + reg) * N + n] = v;
      }
    }
  }
}

// ---------------- fused causal silu-attention, MFMA bf16 (bf16 z in) -------
// att = silu(q k^T + posw[2047+t-s]) * (t<=s);  y = (att @ v) * u
// z row layout (bf16): [u(512) | q(512) | k(512) | v(512)].
#define LDR 72   // LDS row stride in u16 (144 B, 16B-aligned, bank-spread)
__global__ __launch_bounds__(256) void attn_kernel(
    const unsigned short* __restrict__ z, const float* __restrict__ posw,
    float* __restrict__ y) {
  const int qt = blockIdx.x, hh = blockIdx.y, b = blockIdx.z;
  const int s0 = qt * 64;
  __shared__ alignas(16) unsigned short Qs[64 * LDR];
  __shared__ alignas(16) unsigned short Ks[64 * LDR];
  __shared__ alignas(16) unsigned short Vt[64 * LDR];
  __shared__ alignas(16) unsigned short Ps[64 * LDR];
  const unsigned short* zb = z + (size_t)b * S_LEN * 2048;
  const int tid = threadIdx.x;
  const int w = tid >> 6, lane = tid & 63, lm = lane & 15, quad = lane >> 4;

  // ---- stage Q tile (64 x 64 bf16): 512 chunks of 16B ----
#pragma unroll
  for (int p = 0; p < 2; p++) {
    const int g = p * 256 + tid;
    const int r = g >> 3, ch = (g & 7) * 8;
    *reinterpret_cast<us8*>(&Qs[r * LDR + ch]) =
        *reinterpret_cast<const us8*>(zb + (size_t)(s0 + r) * 2048 + 512 + hh * 64 + ch);
  }

  f32x4 O[4] = {};   // output accumulator, C-layout, 16 rows x 64 d per wave

  for (int kt = 0; kt <= qt; kt++) {
    const int t0 = kt * 64;
    __syncthreads();   // prev iteration's readers of Ks/Vt are done
    // ---- stage K tile ----
#pragma unroll
    for (int p = 0; p < 2; p++) {
      const int g = p * 256 + tid;
      const int r = g >> 3, ch = (g & 7) * 8;
      *reinterpret_cast<us8*>(&Ks[r * LDR + ch]) =
          *reinterpret_cast<const us8*>(zb + (size_t)(t0 + r) * 2048 + 1024 + hh * 64 + ch);
    }
    // ---- stage V transposed + swizzled: Vt[d][(tb ^ (d&7))*8 + ti] ----
    {
      const int t = (tid >> 4) * 4;      // 0..60
      const int d = (tid & 15) * 4;      // 0..60
      unsigned short c[4][4];
#pragma unroll
      for (int r = 0; r < 4; r++) {
        const us4 v = *reinterpret_cast<const us4*>(
            zb + (size_t)(t0 + t + r) * 2048 + 1536 + hh * 64 + d);
        c[r][0] = v.x; c[r][1] = v.y; c[r][2] = v.z; c[r][3] = v.w;
      }
      const int tb = t >> 3, ti = t & 7;
#pragma unroll
      for (int j = 0; j < 4; j++) {
        const int dd = d + j;
        us4 o = { c[0][j], c[1][j], c[2][j], c[3][j] };
        *reinterpret_cast<us4*>(&Vt[dd * LDR + ((tb ^ (dd & 7)) << 3) + ti]) = o;
      }
    }
    __syncthreads();   // staging visible to all waves

    // ---- S = Q K^T (16x64 stripe per wave) ----
    const bf16x8 qa0 = *reinterpret_cast<const bf16x8*>(&Qs[(w * 16 + lm) * LDR + quad * 8]);
    const bf16x8 qa1 = *reinterpret_cast<const bf16x8*>(&Qs[(w * 16 + lm) * LDR + 32 + quad * 8]);
    f32x4 S[4];
#pragma unroll
    for (int ct = 0; ct < 4; ct++) {
      const bf16x8 kb0 = *reinterpret_cast<const bf16x8*>(&Ks[(ct * 16 + lm) * LDR + quad * 8]);
      const bf16x8 kb1 = *reinterpret_cast<const bf16x8*>(&Ks[(ct * 16 + lm) * LDR + 32 + quad * 8]);
      f32x4 acc = {};
      acc = __builtin_amdgcn_mfma_f32_16x16x32_bf16(qa0, kb0, acc, 0, 0, 0);
      acc = __builtin_amdgcn_mfma_f32_16x16x32_bf16(qa1, kb1, acc, 0, 0, 0);
      S[ct] = acc;
    }

    // ---- bias + silu + causal mask -> Ps (wave-private stripe, no barrier) --
    {
      const int srow = s0 + w * 16 + quad * 4;
#pragma unroll
      for (int ct = 0; ct < 4; ct++) {
#pragma unroll
        for (int i = 0; i < 4; i++) {
          const int sg = srow + i;
          const int t = t0 + ct * 16 + lm;
          const float x = S[ct][i] + posw[2047 + t - sg];
          const float val = (t <= sg) ? silu_f(x) : 0.f;
          Ps[(w * 16 + quad * 4 + i) * LDR + ct * 16 + lm] = f2bf(val);
        }
      }
    }

    // ---- O += P V (reads own Ps stripe + Vt) ----
    const bf16x8 pa0 = *reinterpret_cast<const bf16x8*>(&Ps[(w * 16 + lm) * LDR + quad * 8]);
    const bf16x8 pa1 = *reinterpret_cast<const bf16x8*>(&Ps[(w * 16 + lm) * LDR + 32 + quad * 8]);
#pragma unroll
    for (int ct = 0; ct < 4; ct++) {
      const int d = ct * 16 + lm;
      const bf16x8 vb0 = *reinterpret_cast<const bf16x8*>(
          &Vt[d * LDR + ((quad ^ (d & 7)) << 3)]);            // k-step 0: tb=quad
      const bf16x8 vb1 = *reinterpret_cast<const bf16x8*>(
          &Vt[d * LDR + (((4 + quad) ^ (d & 7)) << 3)]);      // k-step 1: tb=4+quad
      O[ct] = __builtin_amdgcn_mfma_f32_16x16x32_bf16(pa0, vb0, O[ct], 0, 0, 0);
      O[ct] = __builtin_amdgcn_mfma_f32_16x16x32_bf16(pa1, vb1, O[ct], 0, 0, 0);
    }
  }

  // ---- epilogue: y = O * u ----
  {
    const int srow = s0 + w * 16 + quad * 4;
#pragma unroll
    for (int ct = 0; ct < 4; ct++) {
      const int d = ct * 16 + lm;
#pragma unroll
      for (int i = 0; i < 4; i++) {
        const int sg = srow + i;
        const float u = bf2f(zb[(size_t)sg * 2048 + hh * 64 + d]);
        y[((size_t)(b * S_LEN + sg)) * D_MODEL + hh * 64 + d] = O[ct][i] * u;
      }
    }
  }
}

// ---------------- layer norm (optional residual, f32 and/or bf16 out) ------
__global__ __launch_bounds__(256) void ln_kernel(
    const float* __restrict__ x, const float* __restrict__ res,
    const float* __restrict__ w, const float* __restrict__ bb,
    float* __restrict__ o32, unsigned short* __restrict__ obf) {
  const size_t row = blockIdx.x;
  const int i0 = threadIdx.x, i1 = threadIdx.x + 256;
  float v0 = x[row * D_MODEL + i0];
  float v1 = x[row * D_MODEL + i1];
  if (res) {
    v0 += res[row * D_MODEL + i0];
    v1 += res[row * D_MODEL + i1];
  }
  float s = v0 + v1, ss = v0 * v0 + v1 * v1;
#pragma unroll
  for (int off = 32; off; off >>= 1) {
    s += __shfl_down(s, off, 64);
    ss += __shfl_down(ss, off, 64);
  }
  __shared__ float sbuf[4], ssbuf[4];
  __shared__ float mu_s, rstd_s;
  const int wid = threadIdx.x >> 6, lane = threadIdx.x & 63;
  if (lane == 0) { sbuf[wid] = s; ssbuf[wid] = ss; }
  __syncthreads();
  if (threadIdx.x == 0) {
    const float S = sbuf[0] + sbuf[1] + sbuf[2] + sbuf[3];
    const float SS = ssbuf[0] + ssbuf[1] + ssbuf[2] + ssbuf[3];
    const float mu = S * (1.f / D_MODEL);
    const float var = SS * (1.f / D_MODEL) - mu * mu;
    mu_s = mu;
    rstd_s = rsqrtf(var + 1e-5f);
  }
  __syncthreads();
  const float mu = mu_s, rstd = rstd_s;
  const float r0 = (v0 - mu) * rstd * w[i0] + bb[i0];
  const float r1 = (v1 - mu) * rstd * w[i1] + bb[i1];
  if (o32) {
    o32[row * D_MODEL + i0] = r0;
    o32[row * D_MODEL + i1] = r1;
  }
  if (obf) {
    obf[row * D_MODEL + i0] = f2bf(r0);
    obf[row * D_MODEL + i1] = f2bf(r1);
  }
}

extern "C" void kernel_launch(void* const* d_in, const int* in_sizes, int n_in,
                              void* d_out, int out_size, void* d_ws, size_t ws_size,
                              hipStream_t stream) {
  const int* hist_i = (const int*)d_in[0];
  const int* hist_c = (const int*)d_in[1];
  const int* hlen   = (const int*)d_in[2];
  const int* tgt_i  = (const int*)d_in[3];
  const int* tgt_c  = (const int*)d_in[4];
  const float* item_emb = (const float*)d_in[5];
  const float* cate_emb = (const float*)d_in[6];
  const float* seg_emb  = (const float*)d_in[7];
  const float* W1   = (const float*)d_in[8];    // [4,512,2048]
  const float* b1   = (const float*)d_in[9];    // [4,2048]
  const float* W2   = (const float*)d_in[10];   // [4,512,512]
  const float* b2   = (const float*)d_in[11];   // [4,512]
  const float* ln1w = (const float*)d_in[12];
  const float* ln1b = (const float*)d_in[13];
  const float* ln2w = (const float*)d_in[14];
  const float* ln2b = (const float*)d_in[15];
  const float* posw = (const float*)d_in[16];   // [4,4095]
  const float* lnfw = (const float*)d_in[17];
  const float* lnfb = (const float*)d_in[18];
  float* out = (float*)d_out;

  char* ws = (char*)d_ws;
  float*          h32 = (float*)(ws);                      // 16 MB
  unsigned short* hbf = (unsigned short*)(ws + (16u << 20));  // 8 MB
  unsigned short* zbf = (unsigned short*)(ws + (24u << 20));  // 32 MB
  unsigned short* ybf = (unsigned short*)(ws + (56u << 20));  // 8 MB
  float*          yat = (float*)(ws + (64u << 20));        // 16 MB (aliased t32)
  float*          t32 = yat;
  unsigned short* W1t = (unsigned short*)(ws + (80u << 20));  // 8 MB
  unsigned short* W2t = (unsigned short*)(ws + (88u << 20));  // 2 MB

  const int ROWS = 8 * S_LEN;  // 8192

  transpose_kernel<<<dim3(2048 / 64, 512 / 64, 4), 256, 0, stream>>>(W1, W1t, 512, 2048);
  transpose_kernel<<<dim3(512 / 64, 512 / 64, 4), 256, 0, stream>>>(W2, W2t, 512, 512);
  embed_kernel<<<ROWS, 256, 0, stream>>>(hist_i, hist_c, hlen, tgt_i, tgt_c,
                                         item_emb, cate_emb, seg_emb, h32, hbf);
  for (int l = 0; l < 4; l++) {
    // zbf = silu(h @ W1[l] + b1[l])   [8192, 2048] bf16
    mfma_gemm<1, unsigned short><<<dim3(2048 / 128, ROWS / 128), 256, 0, stream>>>(
        hbf, W1t + (size_t)l * 2048 * 512, b1 + (size_t)l * 2048, zbf, ROWS, 2048, 512);
    // yat = (silu-att @ v) * u        [8192, 512] f32
    attn_kernel<<<dim3(S_LEN / 64, NHEADS, 8), 256, 0, stream>>>(
        zbf, posw + (size_t)l * 4095, yat);
    // ybf = LN1(yat)  (bf16 out only)
    ln_kernel<<<ROWS, 256, 0, stream>>>(yat, nullptr, ln1w + l * 512, ln1b + l * 512,
                                        nullptr, ybf);
    // t32 = ybf @ W2[l] + b2[l]   (aliases yat; yat dead after LN1)
    mfma_gemm<0, float><<<dim3(512 / 128, ROWS / 128), 256, 0, stream>>>(
        ybf, W2t + (size_t)l * 512 * 512, b2 + (size_t)l * 512, t32, ROWS, 512, 512);
    // h = LN2(t32 + h)  (f32 + bf16 out)
    ln_kernel<<<ROWS, 256, 0, stream>>>(t32, h32, ln2w + l * 512, ln2b + l * 512,
                                        h32, hbf);
  }
  // out = LNf(h)
  ln_kernel<<<ROWS, 256, 0, stream>>>(h32, nullptr, lnfw, lnfb, out, nullptr);
}

// Round 4
// 889.834 us; speedup vs baseline: 5.5077x; 1.0878x over previous
//
#include <hip/hip_runtime.h>
#include <cstddef>

// HSTU forward. Round 4: templated-tile MFMA GEMM (gemm2 64x64 for occupancy),
// q128 attention with LDS bias window, wave-per-row LN.
//
// ws layout (90 MB):
//   h32  f32  [8192,512]   @ 0      16 MB   residual stream
//   hbf  bf16 [8192,512]   @ 16 MB   8 MB   GEMM1 A input
//   zbf  bf16 [8192,2048]  @ 24 MB  32 MB   u|q|k|v (GEMM1 out, attn in)
//   ybf  bf16 [8192,512]   @ 56 MB   8 MB   LN1 out (GEMM2 A input)
//   yat  f32  [8192,512]   @ 64 MB  16 MB   attn out; ALIASED by t32 (GEMM2 out)
//   W1t  bf16 [4,2048,512] @ 80 MB   8 MB   transposed bf16 weights
//   W2t  bf16 [4,512,512]  @ 88 MB   2 MB

#define D_MODEL 512
#define S_LEN 1024
#define NHEADS 8

typedef __bf16 bf16x8 __attribute__((ext_vector_type(8)));
typedef float f32x4 __attribute__((ext_vector_type(4)));
typedef unsigned short us4 __attribute__((ext_vector_type(4)));
typedef unsigned short us8 __attribute__((ext_vector_type(8)));

__device__ __forceinline__ float silu_f(float x) {
  return x / (1.f + __expf(-x));
}
__device__ __forceinline__ unsigned short f2bf(float f) {
  unsigned int u = __float_as_uint(f);
  u += 0x7FFF + ((u >> 16) & 1);   // round-to-nearest-even
  return (unsigned short)(u >> 16);
}
__device__ __forceinline__ float bf2f(unsigned short s) {
  return __uint_as_float(((unsigned int)s) << 16);
}
__device__ __forceinline__ void gll16(const void* g, void* l) {
  __builtin_amdgcn_global_load_lds(
      (const __attribute__((address_space(1))) unsigned int*)g,
      (__attribute__((address_space(3))) unsigned int*)l, 16, 0, 0);
}

// ---------------- embedding + id construction (dual f32/bf16 write) --------
__global__ __launch_bounds__(256) void embed_kernel(
    const int* __restrict__ hist_i, const int* __restrict__ hist_c,
    const int* __restrict__ hlen, const int* __restrict__ tgt_i,
    const int* __restrict__ tgt_c, const float* __restrict__ item_emb,
    const float* __restrict__ cate_emb, const float* __restrict__ seg_emb,
    float* __restrict__ h32, unsigned short* __restrict__ hbf) {
  int bs = blockIdx.x;            // b*1024 + s
  int b = bs >> 10, s = bs & 1023;
  int l = hlen[b];
  int id, cid, sg;
  if (s == l)       { id = tgt_i[b]; cid = tgt_c[b]; sg = 1; }
  else if (s < 1023){ id = hist_i[b * 1023 + s]; cid = hist_c[b * 1023 + s]; sg = 0; }
  else              { id = 0; cid = 0; sg = 0; }   // pad column
  const float* ie = item_emb + (size_t)id * D_MODEL;
  const float* ce = cate_emb + (size_t)cid * D_MODEL;
  const float* se = seg_emb + (size_t)sg * D_MODEL;
  float* hr = h32 + (size_t)bs * D_MODEL;
  unsigned short* hb = hbf + (size_t)bs * D_MODEL;
  for (int d = threadIdx.x; d < D_MODEL; d += 256) {
    float v = ie[d] + ce[d] + se[d];
    hr[d] = v;
    hb[d] = f2bf(v);
  }
}

// ---------------- weight transpose + fp32->bf16: Wt[n][k] = W[k][n] --------
__global__ __launch_bounds__(256) void transpose_kernel(
    const float* __restrict__ W, unsigned short* __restrict__ Wt,
    int K, int N) {
  const int l = blockIdx.z;
  W += (size_t)l * K * N;
  Wt += (size_t)l * K * N;
  const int n0 = blockIdx.x * 64, k0 = blockIdx.y * 64;
  __shared__ float T[64][65];
  const int tid = threadIdx.x;
  const int rr = tid >> 4, cc = (tid & 15) * 4;
#pragma unroll
  for (int p = 0; p < 4; p++) {
    const int r = rr + p * 16;
    const float4 v = *reinterpret_cast<const float4*>(&W[(size_t)(k0 + r) * N + n0 + cc]);
    T[r][cc] = v.x; T[r][cc + 1] = v.y; T[r][cc + 2] = v.z; T[r][cc + 3] = v.w;
  }
  __syncthreads();
#pragma unroll
  for (int p = 0; p < 4; p++) {
    const int r = rr + p * 16;       // n within tile
    us4 o = { f2bf(T[cc + 0][r]), f2bf(T[cc + 1][r]),
              f2bf(T[cc + 2][r]), f2bf(T[cc + 3][r]) };
    *reinterpret_cast<us4*>(&Wt[(size_t)(n0 + r) * K + k0 + cc]) = o;
  }
}

// ---------------- bf16 MFMA GEMM: C = epi(A[M,K] @ Bt[N,K]^T + bias) -------
// TMxTN tile, BK=64, 256 threads = 4 waves (2x2), wave tile (TM/2)x(TN/2).
// LDS: As/Bs [rows][64 cols] bf16, xor-swizzled 8-elem chunks.
// Staged with global_load_lds width=16 (lane-linear LDS dest).
template <int TM, int TN, int EPI_SILU, typename OutT>
__global__ __launch_bounds__(256) void mfma_gemm(
    const unsigned short* __restrict__ A, const unsigned short* __restrict__ Bt,
    const float* __restrict__ bias, OutT* __restrict__ C,
    int M, int N, int K) {
  constexpr int MI = TM / 32, NI = TN / 32;   // per-wave 16x16 tiles per dim
  __shared__ unsigned short As[TM * 64];
  __shared__ unsigned short Bs[TN * 64];
  const int tid = threadIdx.x;
  const int w = tid >> 6, lane = tid & 63, lm = lane & 15, quad = lane >> 4;
  const int wm = w & 1, wn = w >> 1;
  const int m0 = blockIdx.y * TM, n0 = blockIdx.x * TN;

  f32x4 acc[MI][NI] = {};

  for (int k0 = 0; k0 < K; k0 += 64) {
    // ---- stage A,B tiles via global_load_lds ----
#pragma unroll
    for (int p = 0; p < TM / 32; p++) {
      const int g = p * 256 + tid;         // 16B chunk id
      const int r = g >> 3;                // tile row
      const int lc = (g & 7) ^ (r & 7);    // logical k-chunk for this phys slot
      gll16(A + (size_t)(m0 + r) * K + k0 + lc * 8, &As[g * 8]);
    }
#pragma unroll
    for (int p = 0; p < TN / 32; p++) {
      const int g = p * 256 + tid;
      const int r = g >> 3;
      const int lc = (g & 7) ^ (r & 7);
      gll16(Bt + (size_t)(n0 + r) * K + k0 + lc * 8, &Bs[g * 8]);
    }
    __syncthreads();
    // ---- compute: 2 k-halves of 32 ----
#pragma unroll
    for (int ki = 0; ki < 2; ki++) {
      bf16x8 af[MI], bfr[NI];
#pragma unroll
      for (int mi = 0; mi < MI; mi++) {
        const int r = wm * (TM / 2) + mi * 16 + lm;
        const int p = (ki * 4 + quad) ^ (lm & 7);
        af[mi] = *reinterpret_cast<const bf16x8*>(&As[r * 64 + p * 8]);
      }
#pragma unroll
      for (int ni = 0; ni < NI; ni++) {
        const int r = wn * (TN / 2) + ni * 16 + lm;
        const int p = (ki * 4 + quad) ^ (lm & 7);
        bfr[ni] = *reinterpret_cast<const bf16x8*>(&Bs[r * 64 + p * 8]);
      }
#pragma unroll
      for (int mi = 0; mi < MI; mi++)
#pragma unroll
        for (int ni = 0; ni < NI; ni++)
          acc[mi][ni] = __builtin_amdgcn_mfma_f32_16x16x32_bf16(
              af[mi], bfr[ni], acc[mi][ni], 0, 0, 0);
    }
    __syncthreads();
  }

  // ---- epilogue: bias (+silu), C-layout col=lm, row=quad*4+reg ----
#pragma unroll
  for (int ni = 0; ni < NI; ni++) {
    const int n = n0 + wn * (TN / 2) + ni * 16 + lm;
    const float bv = bias[n];
#pragma unroll
    for (int mi = 0; mi < MI; mi++) {
      const int mbase = m0 + wm * (TM / 2) + mi * 16 + quad * 4;
#pragma unroll
      for (int reg = 0; reg < 4; reg++) {
        float v = acc[mi][ni][reg] + bv;
        if (EPI_SILU) v = silu_f(v);
        if constexpr (sizeof(OutT) == 2)
          C[(size_t)(mbase + reg) * N + n] = f2bf(v);
        else
          C[(size_t)(mbase + reg) * N + n] = v;
      }
    }
  }
}

// ---------------- fused causal silu-attention, MFMA bf16, q-tile 128 -------
// att = silu(q k^T + posw[2047+t-s]) * (t<=s);  y = (att @ v) * u
// z row layout (bf16): [u(512) | q(512) | k(512) | v(512)].
// Block: one (b, head, 128-row q tile). 4 waves; wave w owns q rows
// [w*32, w*32+32) as two 16-row MFMA stripes (mi=0,1).
#define LDR 72   // LDS row stride in u16 (144 B, 16B-aligned, bank-spread)
__global__ __launch_bounds__(256) void attn_kernel(
    const unsigned short* __restrict__ z, const float* __restrict__ posw,
    float* __restrict__ y) {
  const int qt = blockIdx.x, hh = blockIdx.y, b = blockIdx.z;
  const int s0 = qt * 128;
  __shared__ alignas(16) unsigned short Qs[128 * LDR];
  __shared__ alignas(16) unsigned short Ps[128 * LDR];
  __shared__ alignas(16) unsigned short Ks[64 * LDR];
  __shared__ alignas(16) unsigned short Vt[64 * LDR];
  __shared__ float bias_s[192];
  const unsigned short* zb = z + (size_t)b * S_LEN * 2048;
  const int tid = threadIdx.x;
  const int w = tid >> 6, lane = tid & 63, lm = lane & 15, quad = lane >> 4;

  // ---- stage Q tile (128 x 64 bf16): 1024 chunks of 16B ----
#pragma unroll
  for (int p = 0; p < 4; p++) {
    const int g = p * 256 + tid;
    const int r = g >> 3, ch = (g & 7) * 8;
    *reinterpret_cast<us8*>(&Qs[r * LDR + ch]) =
        *reinterpret_cast<const us8*>(zb + (size_t)(s0 + r) * 2048 + 512 + hh * 64 + ch);
  }

  f32x4 O[2][4] = {};   // [mi][ct] C-layout accumulators (32 rows x 64 d / wave)

  const int ktmax = 2 * qt + 1;
  for (int kt = 0; kt <= ktmax; kt++) {
    const int t0 = kt * 64;
    __syncthreads();   // prev iteration's readers of Ks/Vt/bias_s are done
    // ---- stage K tile (64 x 64) ----
#pragma unroll
    for (int p = 0; p < 2; p++) {
      const int g = p * 256 + tid;
      const int r = g >> 3, ch = (g & 7) * 8;
      *reinterpret_cast<us8*>(&Ks[r * LDR + ch]) =
          *reinterpret_cast<const us8*>(zb + (size_t)(t0 + r) * 2048 + 1024 + hh * 64 + ch);
    }
    // ---- stage V transposed + swizzled: Vt[d][(tb ^ (d&7))*8 + ti] ----
    {
      const int t = (tid >> 4) * 4;      // 0..60
      const int d = (tid & 15) * 4;      // 0..60
      unsigned short c[4][4];
#pragma unroll
      for (int r = 0; r < 4; r++) {
        const us4 v = *reinterpret_cast<const us4*>(
            zb + (size_t)(t0 + t + r) * 2048 + 1536 + hh * 64 + d);
        c[r][0] = v.x; c[r][1] = v.y; c[r][2] = v.z; c[r][3] = v.w;
      }
      const int tb = t >> 3, ti = t & 7;
#pragma unroll
      for (int j = 0; j < 4; j++) {
        const int dd = d + j;
        us4 o = { c[0][j], c[1][j], c[2][j], c[3][j] };
        *reinterpret_cast<us4*>(&Vt[dd * LDR + ((tb ^ (dd & 7)) << 3) + ti]) = o;
      }
    }
    // ---- stage posw window: t-s in [t0-s0-127, t0-s0+63] (191 vals) ----
    if (tid < 192) bias_s[tid] = posw[2047 + t0 - s0 - 127 + tid];
    __syncthreads();   // staging visible to all waves

#pragma unroll
    for (int mi = 0; mi < 2; mi++) {
      const int qrow = w * 32 + mi * 16;
      // ---- S = Q K^T (16x64 stripe) ----
      const bf16x8 qa0 = *reinterpret_cast<const bf16x8*>(&Qs[(qrow + lm) * LDR + quad * 8]);
      const bf16x8 qa1 = *reinterpret_cast<const bf16x8*>(&Qs[(qrow + lm) * LDR + 32 + quad * 8]);
#pragma unroll
      for (int ct = 0; ct < 4; ct++) {
        const bf16x8 kb0 = *reinterpret_cast<const bf16x8*>(&Ks[(ct * 16 + lm) * LDR + quad * 8]);
        const bf16x8 kb1 = *reinterpret_cast<const bf16x8*>(&Ks[(ct * 16 + lm) * LDR + 32 + quad * 8]);
        f32x4 acc = {};
        acc = __builtin_amdgcn_mfma_f32_16x16x32_bf16(qa0, kb0, acc, 0, 0, 0);
        acc = __builtin_amdgcn_mfma_f32_16x16x32_bf16(qa1, kb1, acc, 0, 0, 0);
        // ---- bias + silu + causal -> Ps (wave-private stripe) ----
        const int bbase = 127 - (qrow + quad * 4);   // + (t - t0) - i
#pragma unroll
        for (int i = 0; i < 4; i++) {
          const int sg = s0 + qrow + quad * 4 + i;
          const int t = t0 + ct * 16 + lm;
          const float x = acc[i] + bias_s[bbase + ct * 16 + lm - i];
          const float val = (t <= sg) ? silu_f(x) : 0.f;
          Ps[(qrow + quad * 4 + i) * LDR + ct * 16 + lm] = f2bf(val);
        }
      }
    }

    // ---- O += P V (reads own Ps stripes + Vt) ----
    bf16x8 pa0[2], pa1[2];
#pragma unroll
    for (int mi = 0; mi < 2; mi++) {
      const int qrow = w * 32 + mi * 16;
      pa0[mi] = *reinterpret_cast<const bf16x8*>(&Ps[(qrow + lm) * LDR + quad * 8]);
      pa1[mi] = *reinterpret_cast<const bf16x8*>(&Ps[(qrow + lm) * LDR + 32 + quad * 8]);
    }
#pragma unroll
    for (int ct = 0; ct < 4; ct++) {
      const int d = ct * 16 + lm;
      const bf16x8 vb0 = *reinterpret_cast<const bf16x8*>(
          &Vt[d * LDR + ((quad ^ (d & 7)) << 3)]);            // k-step 0: tb=quad
      const bf16x8 vb1 = *reinterpret_cast<const bf16x8*>(
          &Vt[d * LDR + (((4 + quad) ^ (d & 7)) << 3)]);      // k-step 1: tb=4+quad
#pragma unroll
      for (int mi = 0; mi < 2; mi++) {
        O[mi][ct] = __builtin_amdgcn_mfma_f32_16x16x32_bf16(pa0[mi], vb0, O[mi][ct], 0, 0, 0);
        O[mi][ct] = __builtin_amdgcn_mfma_f32_16x16x32_bf16(pa1[mi], vb1, O[mi][ct], 0, 0, 0);
      }
    }
  }

  // ---- epilogue: y = O * u ----
#pragma unroll
  for (int mi = 0; mi < 2; mi++) {
    const int srow = s0 + w * 32 + mi * 16 + quad * 4;
#pragma unroll
    for (int ct = 0; ct < 4; ct++) {
      const int d = ct * 16 + lm;
#pragma unroll
      for (int i = 0; i < 4; i++) {
        const int sg = srow + i;
        const float u = bf2f(zb[(size_t)sg * 2048 + hh * 64 + d]);
        y[((size_t)(b * S_LEN + sg)) * D_MODEL + hh * 64 + d] = O[mi][ct][i] * u;
      }
    }
  }
}

// ---------------- layer norm: one wave per row, no barriers ----------------
__global__ __launch_bounds__(256) void ln_kernel(
    const float* __restrict__ x, const float* __restrict__ res,
    const float* __restrict__ w, const float* __restrict__ bb,
    float* __restrict__ o32, unsigned short* __restrict__ obf) {
  const int wv = threadIdx.x >> 6, lane = threadIdx.x & 63;
  const size_t row = blockIdx.x * 4 + wv;
  const int i0 = lane * 4, i1 = 256 + lane * 4;
  float4 v0 = *reinterpret_cast<const float4*>(&x[row * D_MODEL + i0]);
  float4 v1 = *reinterpret_cast<const float4*>(&x[row * D_MODEL + i1]);
  if (res) {
    const float4 r0 = *reinterpret_cast<const float4*>(&res[row * D_MODEL + i0]);
    const float4 r1 = *reinterpret_cast<const float4*>(&res[row * D_MODEL + i1]);
    v0.x += r0.x; v0.y += r0.y; v0.z += r0.z; v0.w += r0.w;
    v1.x += r1.x; v1.y += r1.y; v1.z += r1.z; v1.w += r1.w;
  }
  float s = v0.x + v0.y + v0.z + v0.w + v1.x + v1.y + v1.z + v1.w;
  float ss = v0.x * v0.x + v0.y * v0.y + v0.z * v0.z + v0.w * v0.w +
             v1.x * v1.x + v1.y * v1.y + v1.z * v1.z + v1.w * v1.w;
#pragma unroll
  for (int off = 32; off; off >>= 1) {
    s += __shfl_down(s, off, 64);
    ss += __shfl_down(ss, off, 64);
  }
  s = __shfl(s, 0, 64);
  ss = __shfl(ss, 0, 64);
  const float mu = s * (1.f / D_MODEL);
  const float rstd = rsqrtf(ss * (1.f / D_MODEL) - mu * mu + 1e-5f);
  const float4 w0 = *reinterpret_cast<const float4*>(&w[i0]);
  const float4 w1 = *reinterpret_cast<const float4*>(&w[i1]);
  const float4 b0 = *reinterpret_cast<const float4*>(&bb[i0]);
  const float4 b1 = *reinterpret_cast<const float4*>(&bb[i1]);
  float r[8];
  r[0] = (v0.x - mu) * rstd * w0.x + b0.x;
  r[1] = (v0.y - mu) * rstd * w0.y + b0.y;
  r[2] = (v0.z - mu) * rstd * w0.z + b0.z;
  r[3] = (v0.w - mu) * rstd * w0.w + b0.w;
  r[4] = (v1.x - mu) * rstd * w1.x + b1.x;
  r[5] = (v1.y - mu) * rstd * w1.y + b1.y;
  r[6] = (v1.z - mu) * rstd * w1.z + b1.z;
  r[7] = (v1.w - mu) * rstd * w1.w + b1.w;
  if (o32) {
    *reinterpret_cast<float4*>(&o32[row * D_MODEL + i0]) = make_float4(r[0], r[1], r[2], r[3]);
    *reinterpret_cast<float4*>(&o32[row * D_MODEL + i1]) = make_float4(r[4], r[5], r[6], r[7]);
  }
  if (obf) {
    us4 q0 = { f2bf(r[0]), f2bf(r[1]), f2bf(r[2]), f2bf(r[3]) };
    us4 q1 = { f2bf(r[4]), f2bf(r[5]), f2bf(r[6]), f2bf(r[7]) };
    *reinterpret_cast<us4*>(&obf[row * D_MODEL + i0]) = q0;
    *reinterpret_cast<us4*>(&obf[row * D_MODEL + i1]) = q1;
  }
}

extern "C" void kernel_launch(void* const* d_in, const int* in_sizes, int n_in,
                              void* d_out, int out_size, void* d_ws, size_t ws_size,
                              hipStream_t stream) {
  const int* hist_i = (const int*)d_in[0];
  const int* hist_c = (const int*)d_in[1];
  const int* hlen   = (const int*)d_in[2];
  const int* tgt_i  = (const int*)d_in[3];
  const int* tgt_c  = (const int*)d_in[4];
  const float* item_emb = (const float*)d_in[5];
  const float* cate_emb = (const float*)d_in[6];
  const float* seg_emb  = (const float*)d_in[7];
  const float* W1   = (const float*)d_in[8];    // [4,512,2048]
  const float* b1   = (const float*)d_in[9];    // [4,2048]
  const float* W2   = (const float*)d_in[10];   // [4,512,512]
  const float* b2   = (const float*)d_in[11];   // [4,512]
  const float* ln1w = (const float*)d_in[12];
  const float* ln1b = (const float*)d_in[13];
  const float* ln2w = (const float*)d_in[14];
  const float* ln2b = (const float*)d_in[15];
  const float* posw = (const float*)d_in[16];   // [4,4095]
  const float* lnfw = (const float*)d_in[17];
  const float* lnfb = (const float*)d_in[18];
  float* out = (float*)d_out;

  char* ws = (char*)d_ws;
  float*          h32 = (float*)(ws);                      // 16 MB
  unsigned short* hbf = (unsigned short*)(ws + (16u << 20));  // 8 MB
  unsigned short* zbf = (unsigned short*)(ws + (24u << 20));  // 32 MB
  unsigned short* ybf = (unsigned short*)(ws + (56u << 20));  // 8 MB
  float*          yat = (float*)(ws + (64u << 20));        // 16 MB (aliased t32)
  float*          t32 = yat;
  unsigned short* W1t = (unsigned short*)(ws + (80u << 20));  // 8 MB
  unsigned short* W2t = (unsigned short*)(ws + (88u << 20));  // 2 MB

  const int ROWS = 8 * S_LEN;  // 8192

  transpose_kernel<<<dim3(2048 / 64, 512 / 64, 4), 256, 0, stream>>>(W1, W1t, 512, 2048);
  transpose_kernel<<<dim3(512 / 64, 512 / 64, 4), 256, 0, stream>>>(W2, W2t, 512, 512);
  embed_kernel<<<ROWS, 256, 0, stream>>>(hist_i, hist_c, hlen, tgt_i, tgt_c,
                                         item_emb, cate_emb, seg_emb, h32, hbf);
  for (int l = 0; l < 4; l++) {
    // zbf = silu(h @ W1[l] + b1[l])   [8192, 2048] bf16
    mfma_gemm<128, 128, 1, unsigned short><<<dim3(2048 / 128, ROWS / 128), 256, 0, stream>>>(
        hbf, W1t + (size_t)l * 2048 * 512, b1 + (size_t)l * 2048, zbf, ROWS, 2048, 512);
    // yat = (silu-att @ v) * u        [8192, 512] f32
    attn_kernel<<<dim3(S_LEN / 128, NHEADS, 8), 256, 0, stream>>>(
        zbf, posw + (size_t)l * 4095, yat);
    // ybf = LN1(yat)  (bf16 out only)
    ln_kernel<<<ROWS / 4, 256, 0, stream>>>(yat, nullptr, ln1w + l * 512, ln1b + l * 512,
                                            nullptr, ybf);
    // t32 = ybf @ W2[l] + b2[l]   (aliases yat; yat dead after LN1)
    mfma_gemm<64, 64, 0, float><<<dim3(512 / 64, ROWS / 64), 256, 0, stream>>>(
        ybf, W2t + (size_t)l * 512 * 512, b2 + (size_t)l * 512, t32, ROWS, 512, 512);
    // h = LN2(t32 + h)  (f32 + bf16 out)
    ln_kernel<<<ROWS / 4, 256, 0, stream>>>(t32, h32, ln2w + l * 512, ln2b + l * 512,
                                            h32, hbf);
  }
  // out = LNf(h)
  ln_kernel<<<ROWS / 4, 256, 0, stream>>>(h32, nullptr, lnfw, lnfb, out, nullptr);
}

// Round 5
// 819.159 us; speedup vs baseline: 5.9829x; 1.0863x over previous
//
#include <hip/hip_runtime.h>
#include <cstddef>

// HSTU forward. Round 5: S^T-layout attention (Q in regs, balanced qt pairs,
// vectorized Ps writes), gemm1 256x128 + XCD swizzle.
//
// ws layout (90 MB):
//   h32  f32  [8192,512]   @ 0      16 MB   residual stream
//   hbf  bf16 [8192,512]   @ 16 MB   8 MB   GEMM1 A input
//   zbf  bf16 [8192,2048]  @ 24 MB  32 MB   u|q|k|v (GEMM1 out, attn in)
//   ybf  bf16 [8192,512]   @ 56 MB   8 MB   LN1 out (GEMM2 A input)
//   yat  f32  [8192,512]   @ 64 MB  16 MB   attn out; ALIASED by t32 (GEMM2 out)
//   W1t  bf16 [4,2048,512] @ 80 MB   8 MB   transposed bf16 weights
//   W2t  bf16 [4,512,512]  @ 88 MB   2 MB

#define D_MODEL 512
#define S_LEN 1024
#define NHEADS 8

typedef __bf16 bf16x8 __attribute__((ext_vector_type(8)));
typedef float f32x4 __attribute__((ext_vector_type(4)));
typedef unsigned short us4 __attribute__((ext_vector_type(4)));
typedef unsigned short us8 __attribute__((ext_vector_type(8)));

__device__ __forceinline__ float silu_f(float x) {
  return x / (1.f + __expf(-x));
}
__device__ __forceinline__ unsigned short f2bf(float f) {
  unsigned int u = __float_as_uint(f);
  u += 0x7FFF + ((u >> 16) & 1);   // round-to-nearest-even
  return (unsigned short)(u >> 16);
}
__device__ __forceinline__ float bf2f(unsigned short s) {
  return __uint_as_float(((unsigned int)s) << 16);
}
__device__ __forceinline__ void gll16(const void* g, void* l) {
  __builtin_amdgcn_global_load_lds(
      (const __attribute__((address_space(1))) unsigned int*)g,
      (__attribute__((address_space(3))) unsigned int*)l, 16, 0, 0);
}

// ---------------- embedding + id construction (dual f32/bf16 write) --------
__global__ __launch_bounds__(256) void embed_kernel(
    const int* __restrict__ hist_i, const int* __restrict__ hist_c,
    const int* __restrict__ hlen, const int* __restrict__ tgt_i,
    const int* __restrict__ tgt_c, const float* __restrict__ item_emb,
    const float* __restrict__ cate_emb, const float* __restrict__ seg_emb,
    float* __restrict__ h32, unsigned short* __restrict__ hbf) {
  int bs = blockIdx.x;            // b*1024 + s
  int b = bs >> 10, s = bs & 1023;
  int l = hlen[b];
  int id, cid, sg;
  if (s == l)       { id = tgt_i[b]; cid = tgt_c[b]; sg = 1; }
  else if (s < 1023){ id = hist_i[b * 1023 + s]; cid = hist_c[b * 1023 + s]; sg = 0; }
  else              { id = 0; cid = 0; sg = 0; }   // pad column
  const float* ie = item_emb + (size_t)id * D_MODEL;
  const float* ce = cate_emb + (size_t)cid * D_MODEL;
  const float* se = seg_emb + (size_t)sg * D_MODEL;
  float* hr = h32 + (size_t)bs * D_MODEL;
  unsigned short* hb = hbf + (size_t)bs * D_MODEL;
  for (int d = threadIdx.x; d < D_MODEL; d += 256) {
    float v = ie[d] + ce[d] + se[d];
    hr[d] = v;
    hb[d] = f2bf(v);
  }
}

// ---------------- weight transpose + fp32->bf16: Wt[n][k] = W[k][n] --------
__global__ __launch_bounds__(256) void transpose_kernel(
    const float* __restrict__ W, unsigned short* __restrict__ Wt,
    int K, int N) {
  const int l = blockIdx.z;
  W += (size_t)l * K * N;
  Wt += (size_t)l * K * N;
  const int n0 = blockIdx.x * 64, k0 = blockIdx.y * 64;
  __shared__ float T[64][65];
  const int tid = threadIdx.x;
  const int rr = tid >> 4, cc = (tid & 15) * 4;
#pragma unroll
  for (int p = 0; p < 4; p++) {
    const int r = rr + p * 16;
    const float4 v = *reinterpret_cast<const float4*>(&W[(size_t)(k0 + r) * N + n0 + cc]);
    T[r][cc] = v.x; T[r][cc + 1] = v.y; T[r][cc + 2] = v.z; T[r][cc + 3] = v.w;
  }
  __syncthreads();
#pragma unroll
  for (int p = 0; p < 4; p++) {
    const int r = rr + p * 16;       // n within tile
    us4 o = { f2bf(T[cc + 0][r]), f2bf(T[cc + 1][r]),
              f2bf(T[cc + 2][r]), f2bf(T[cc + 3][r]) };
    *reinterpret_cast<us4*>(&Wt[(size_t)(n0 + r) * K + k0 + cc]) = o;
  }
}

// ---------------- bf16 MFMA GEMM: C = epi(A[M,K] @ Bt[N,K]^T + bias) -------
// TMxTN tile, BK=64, 256 threads = 4 waves (2x2), wave tile (TM/2)x(TN/2).
// LDS: As/Bs [rows][64 cols] bf16, xor-swizzled 8-elem chunks.
// SWZ=1: 1D grid, XCD-aware decode (id&7 = XCD; A-stripe + B stay in L2).
template <int TM, int TN, int SWZ, int EPI_SILU, typename OutT>
__global__ __launch_bounds__(256) void mfma_gemm(
    const unsigned short* __restrict__ A, const unsigned short* __restrict__ Bt,
    const float* __restrict__ bias, OutT* __restrict__ C,
    int M, int N, int K) {
  constexpr int MI = TM / 32, NI = TN / 32;   // per-wave 16x16 tiles per dim
  __shared__ unsigned short As[TM * 64];
  __shared__ unsigned short Bs[TN * 64];
  const int tid = threadIdx.x;
  const int w = tid >> 6, lane = tid & 63, lm = lane & 15, quad = lane >> 4;
  const int wm = w & 1, wn = w >> 1;
  int m0, n0;
  if (SWZ) {
    // 512 blocks: xcd=id&7 owns m-blocks [xcd*4, xcd*4+4) x all n-blocks
    const int id = blockIdx.x;
    const int xcd = id & 7, j = id >> 3;
    m0 = (xcd * 4 + (j & 3)) * TM;
    n0 = (j >> 2) * TN;
  } else {
    m0 = blockIdx.y * TM;
    n0 = blockIdx.x * TN;
  }

  f32x4 acc[MI][NI] = {};

  for (int k0 = 0; k0 < K; k0 += 64) {
    // ---- stage A,B tiles via global_load_lds ----
#pragma unroll
    for (int p = 0; p < TM / 32; p++) {
      const int g = p * 256 + tid;         // 16B chunk id
      const int r = g >> 3;                // tile row
      const int lc = (g & 7) ^ (r & 7);    // logical k-chunk for this phys slot
      gll16(A + (size_t)(m0 + r) * K + k0 + lc * 8, &As[g * 8]);
    }
#pragma unroll
    for (int p = 0; p < TN / 32; p++) {
      const int g = p * 256 + tid;
      const int r = g >> 3;
      const int lc = (g & 7) ^ (r & 7);
      gll16(Bt + (size_t)(n0 + r) * K + k0 + lc * 8, &Bs[g * 8]);
    }
    __syncthreads();
    // ---- compute: 2 k-halves of 32 ----
#pragma unroll
    for (int ki = 0; ki < 2; ki++) {
      bf16x8 af[MI], bfr[NI];
#pragma unroll
      for (int mi = 0; mi < MI; mi++) {
        const int r = wm * (TM / 2) + mi * 16 + lm;
        const int p = (ki * 4 + quad) ^ (lm & 7);
        af[mi] = *reinterpret_cast<const bf16x8*>(&As[r * 64 + p * 8]);
      }
#pragma unroll
      for (int ni = 0; ni < NI; ni++) {
        const int r = wn * (TN / 2) + ni * 16 + lm;
        const int p = (ki * 4 + quad) ^ (lm & 7);
        bfr[ni] = *reinterpret_cast<const bf16x8*>(&Bs[r * 64 + p * 8]);
      }
#pragma unroll
      for (int mi = 0; mi < MI; mi++)
#pragma unroll
        for (int ni = 0; ni < NI; ni++)
          acc[mi][ni] = __builtin_amdgcn_mfma_f32_16x16x32_bf16(
              af[mi], bfr[ni], acc[mi][ni], 0, 0, 0);
    }
    __syncthreads();
  }

  // ---- epilogue: bias (+silu), C-layout col=lm, row=quad*4+reg ----
#pragma unroll
  for (int ni = 0; ni < NI; ni++) {
    const int n = n0 + wn * (TN / 2) + ni * 16 + lm;
    const float bv = bias[n];
#pragma unroll
    for (int mi = 0; mi < MI; mi++) {
      const int mbase = m0 + wm * (TM / 2) + mi * 16 + quad * 4;
#pragma unroll
      for (int reg = 0; reg < 4; reg++) {
        float v = acc[mi][ni][reg] + bv;
        if (EPI_SILU) v = silu_f(v);
        if constexpr (sizeof(OutT) == 2)
          C[(size_t)(mbase + reg) * N + n] = f2bf(v);
        else
          C[(size_t)(mbase + reg) * N + n] = v;
      }
    }
  }
}

// ---------------- fused causal silu-attention, S^T layout ------------------
// att = silu(q k^T + posw[2047+t-s]) * (t<=s);  y = (att @ v) * u
// z row layout (bf16): [u(512) | q(512) | k(512) | v(512)].
// Block: (qt-pair, head, b). Processes q64 tiles qt=blockIdx.x and 15-qt:
// kt-units = (qtA+1)+(qtB+1) = 17 for every block -> perfect balance.
// S^T trick: compute S^T = K Q^T (A=K rows t, B=Q rows s). C-layout gives
// lane (quad,lm): t = tt*16+quad*4+i, s = w*16+lm -> 4 t-consecutive P values
// per lane => us4 ds_write_b64 into Ps[s][t]; PV A-frag = ds_read_b128.
// Q is kept in registers (B-operand frags loaded from global once per tile).
#define LDR 72   // LDS row stride in u16 (144 B, 16B-aligned, bank-spread)
__global__ __launch_bounds__(256) void attn_kernel(
    const unsigned short* __restrict__ z, const float* __restrict__ posw,
    float* __restrict__ y) {
  const int hh = blockIdx.y, b = blockIdx.z;
  __shared__ alignas(16) unsigned short Ks[64 * LDR];
  __shared__ alignas(16) unsigned short Vt[64 * LDR];
  __shared__ alignas(16) unsigned short Ps[64 * LDR];
  __shared__ float bias_s[128];
  const unsigned short* zb = z + (size_t)b * S_LEN * 2048;
  const int tid = threadIdx.x;
  const int w = tid >> 6, lane = tid & 63, lm = lane & 15, quad = lane >> 4;

#pragma unroll
  for (int phase = 0; phase < 2; phase++) {
    const int qt = phase == 0 ? (int)blockIdx.x : 15 - (int)blockIdx.x;
    const int s0 = qt * 64;
    const int srow = s0 + w * 16 + lm;   // this lane's q row (as B-operand n)

    // ---- Q fragments in registers (B-operand): Q[srow][ki*32+quad*8 ..+8] --
    const bf16x8 qb0 = *reinterpret_cast<const bf16x8*>(
        zb + (size_t)srow * 2048 + 512 + hh * 64 + quad * 8);
    const bf16x8 qb1 = *reinterpret_cast<const bf16x8*>(
        zb + (size_t)srow * 2048 + 512 + hh * 64 + 32 + quad * 8);

    f32x4 O[4] = {};   // O[s 16][d 64] per wave; col=d-in-tile, row=quad*4+reg

    for (int kt = 0; kt <= qt; kt++) {
      const int t0 = kt * 64;
      __syncthreads();   // prev iter (or prev phase) readers of Ks/Vt done
      // ---- stage K tile (64 x 64) ----
#pragma unroll
      for (int p = 0; p < 2; p++) {
        const int g = p * 256 + tid;
        const int r = g >> 3, ch = (g & 7) * 8;
        *reinterpret_cast<us8*>(&Ks[r * LDR + ch]) =
            *reinterpret_cast<const us8*>(zb + (size_t)(t0 + r) * 2048 + 1024 + hh * 64 + ch);
      }
      // ---- stage V transposed + swizzled: Vt[d][(tb ^ (d&7))*8 + ti] ----
      {
        const int t = (tid >> 4) * 4;      // 0..60
        const int d = (tid & 15) * 4;      // 0..60
        unsigned short c[4][4];
#pragma unroll
        for (int r = 0; r < 4; r++) {
          const us4 v = *reinterpret_cast<const us4*>(
              zb + (size_t)(t0 + t + r) * 2048 + 1536 + hh * 64 + d);
          c[r][0] = v.x; c[r][1] = v.y; c[r][2] = v.z; c[r][3] = v.w;
        }
        const int tb = t >> 3, ti = t & 7;
#pragma unroll
        for (int j = 0; j < 4; j++) {
          const int dd = d + j;
          us4 o = { c[0][j], c[1][j], c[2][j], c[3][j] };
          *reinterpret_cast<us4*>(&Vt[dd * LDR + ((tb ^ (dd & 7)) << 3) + ti]) = o;
        }
      }
      // ---- stage posw window: t-s in [t0-s0-63, t0-s0+63] ----
      if (tid < 128) bias_s[tid] = posw[2047 + t0 - s0 - 63 + tid];
      __syncthreads();   // staging visible to all waves

      // ---- S^T = K Q^T : 4 t-tiles x (16 s-cols per wave) ----
#pragma unroll
      for (int tt = 0; tt < 4; tt++) {
        const bf16x8 ka0 = *reinterpret_cast<const bf16x8*>(&Ks[(tt * 16 + lm) * LDR + quad * 8]);
        const bf16x8 ka1 = *reinterpret_cast<const bf16x8*>(&Ks[(tt * 16 + lm) * LDR + 32 + quad * 8]);
        f32x4 st = {};
        st = __builtin_amdgcn_mfma_f32_16x16x32_bf16(ka0, qb0, st, 0, 0, 0);
        st = __builtin_amdgcn_mfma_f32_16x16x32_bf16(ka1, qb1, st, 0, 0, 0);
        // lane holds t = t0 + tt*16 + quad*4 + i,  s = srow
        const int bbase = 63 + tt * 16 + quad * 4 - w * 16 - lm;  // + i
        const int tq = t0 + tt * 16 + quad * 4;
        us4 pv;
        unsigned short* pp = (unsigned short*)&pv;
#pragma unroll
        for (int i = 0; i < 4; i++) {
          const float x = st[i] + bias_s[bbase + i];
          const float val = (tq + i <= srow) ? silu_f(x) : 0.f;
          pp[i] = f2bf(val);
        }
        // Ps[s][t]: wave-private rows [w*16, w*16+16)
        *reinterpret_cast<us4*>(&Ps[(w * 16 + lm) * LDR + tt * 16 + quad * 4]) = pv;
      }

      // ---- O += P V  (A = Ps stripe, B = Vt) ----
      const bf16x8 pa0 = *reinterpret_cast<const bf16x8*>(&Ps[(w * 16 + lm) * LDR + quad * 8]);
      const bf16x8 pa1 = *reinterpret_cast<const bf16x8*>(&Ps[(w * 16 + lm) * LDR + 32 + quad * 8]);
#pragma unroll
      for (int ct = 0; ct < 4; ct++) {
        const int d = ct * 16 + lm;
        const bf16x8 vb0 = *reinterpret_cast<const bf16x8*>(
            &Vt[d * LDR + ((quad ^ (d & 7)) << 3)]);            // tb=quad
        const bf16x8 vb1 = *reinterpret_cast<const bf16x8*>(
            &Vt[d * LDR + (((4 + quad) ^ (d & 7)) << 3)]);      // tb=4+quad
        O[ct] = __builtin_amdgcn_mfma_f32_16x16x32_bf16(pa0, vb0, O[ct], 0, 0, 0);
        O[ct] = __builtin_amdgcn_mfma_f32_16x16x32_bf16(pa1, vb1, O[ct], 0, 0, 0);
      }
    }

    // ---- epilogue: y = O * u ----
    {
      const int sbase = s0 + w * 16 + quad * 4;
#pragma unroll
      for (int ct = 0; ct < 4; ct++) {
        const int d = ct * 16 + lm;
#pragma unroll
        for (int i = 0; i < 4; i++) {
          const int sg = sbase + i;
          const float u = bf2f(zb[(size_t)sg * 2048 + hh * 64 + d]);
          y[((size_t)(b * S_LEN + sg)) * D_MODEL + hh * 64 + d] = O[ct][i] * u;
        }
      }
    }
  }
}

// ---------------- layer norm: one wave per row, no barriers ----------------
__global__ __launch_bounds__(256) void ln_kernel(
    const float* __restrict__ x, const float* __restrict__ res,
    const float* __restrict__ w, const float* __restrict__ bb,
    float* __restrict__ o32, unsigned short* __restrict__ obf) {
  const int wv = threadIdx.x >> 6, lane = threadIdx.x & 63;
  const size_t row = blockIdx.x * 4 + wv;
  const int i0 = lane * 4, i1 = 256 + lane * 4;
  float4 v0 = *reinterpret_cast<const float4*>(&x[row * D_MODEL + i0]);
  float4 v1 = *reinterpret_cast<const float4*>(&x[row * D_MODEL + i1]);
  if (res) {
    const float4 r0 = *reinterpret_cast<const float4*>(&res[row * D_MODEL + i0]);
    const float4 r1 = *reinterpret_cast<const float4*>(&res[row * D_MODEL + i1]);
    v0.x += r0.x; v0.y += r0.y; v0.z += r0.z; v0.w += r0.w;
    v1.x += r1.x; v1.y += r1.y; v1.z += r1.z; v1.w += r1.w;
  }
  float s = v0.x + v0.y + v0.z + v0.w + v1.x + v1.y + v1.z + v1.w;
  float ss = v0.x * v0.x + v0.y * v0.y + v0.z * v0.z + v0.w * v0.w +
             v1.x * v1.x + v1.y * v1.y + v1.z * v1.z + v1.w * v1.w;
#pragma unroll
  for (int off = 32; off; off >>= 1) {
    s += __shfl_down(s, off, 64);
    ss += __shfl_down(ss, off, 64);
  }
  s = __shfl(s, 0, 64);
  ss = __shfl(ss, 0, 64);
  const float mu = s * (1.f / D_MODEL);
  const float rstd = rsqrtf(ss * (1.f / D_MODEL) - mu * mu + 1e-5f);
  const float4 w0 = *reinterpret_cast<const float4*>(&w[i0]);
  const float4 w1 = *reinterpret_cast<const float4*>(&w[i1]);
  const float4 b0 = *reinterpret_cast<const float4*>(&bb[i0]);
  const float4 b1 = *reinterpret_cast<const float4*>(&bb[i1]);
  float r[8];
  r[0] = (v0.x - mu) * rstd * w0.x + b0.x;
  r[1] = (v0.y - mu) * rstd * w0.y + b0.y;
  r[2] = (v0.z - mu) * rstd * w0.z + b0.z;
  r[3] = (v0.w - mu) * rstd * w0.w + b0.w;
  r[4] = (v1.x - mu) * rstd * w1.x + b1.x;
  r[5] = (v1.y - mu) * rstd * w1.y + b1.y;
  r[6] = (v1.z - mu) * rstd * w1.z + b1.z;
  r[7] = (v1.w - mu) * rstd * w1.w + b1.w;
  if (o32) {
    *reinterpret_cast<float4*>(&o32[row * D_MODEL + i0]) = make_float4(r[0], r[1], r[2], r[3]);
    *reinterpret_cast<float4*>(&o32[row * D_MODEL + i1]) = make_float4(r[4], r[5], r[6], r[7]);
  }
  if (obf) {
    us4 q0 = { f2bf(r[0]), f2bf(r[1]), f2bf(r[2]), f2bf(r[3]) };
    us4 q1 = { f2bf(r[4]), f2bf(r[5]), f2bf(r[6]), f2bf(r[7]) };
    *reinterpret_cast<us4*>(&obf[row * D_MODEL + i0]) = q0;
    *reinterpret_cast<us4*>(&obf[row * D_MODEL + i1]) = q1;
  }
}

extern "C" void kernel_launch(void* const* d_in, const int* in_sizes, int n_in,
                              void* d_out, int out_size, void* d_ws, size_t ws_size,
                              hipStream_t stream) {
  const int* hist_i = (const int*)d_in[0];
  const int* hist_c = (const int*)d_in[1];
  const int* hlen   = (const int*)d_in[2];
  const int* tgt_i  = (const int*)d_in[3];
  const int* tgt_c  = (const int*)d_in[4];
  const float* item_emb = (const float*)d_in[5];
  const float* cate_emb = (const float*)d_in[6];
  const float* seg_emb  = (const float*)d_in[7];
  const float* W1   = (const float*)d_in[8];    // [4,512,2048]
  const float* b1   = (const float*)d_in[9];    // [4,2048]
  const float* W2   = (const float*)d_in[10];   // [4,512,512]
  const float* b2   = (const float*)d_in[11];   // [4,512]
  const float* ln1w = (const float*)d_in[12];
  const float* ln1b = (const float*)d_in[13];
  const float* ln2w = (const float*)d_in[14];
  const float* ln2b = (const float*)d_in[15];
  const float* posw = (const float*)d_in[16];   // [4,4095]
  const float* lnfw = (const float*)d_in[17];
  const float* lnfb = (const float*)d_in[18];
  float* out = (float*)d_out;

  char* ws = (char*)d_ws;
  float*          h32 = (float*)(ws);                      // 16 MB
  unsigned short* hbf = (unsigned short*)(ws + (16u << 20));  // 8 MB
  unsigned short* zbf = (unsigned short*)(ws + (24u << 20));  // 32 MB
  unsigned short* ybf = (unsigned short*)(ws + (56u << 20));  // 8 MB
  float*          yat = (float*)(ws + (64u << 20));        // 16 MB (aliased t32)
  float*          t32 = yat;
  unsigned short* W1t = (unsigned short*)(ws + (80u << 20));  // 8 MB
  unsigned short* W2t = (unsigned short*)(ws + (88u << 20));  // 2 MB

  const int ROWS = 8 * S_LEN;  // 8192

  transpose_kernel<<<dim3(2048 / 64, 512 / 64, 4), 256, 0, stream>>>(W1, W1t, 512, 2048);
  transpose_kernel<<<dim3(512 / 64, 512 / 64, 4), 256, 0, stream>>>(W2, W2t, 512, 512);
  embed_kernel<<<ROWS, 256, 0, stream>>>(hist_i, hist_c, hlen, tgt_i, tgt_c,
                                         item_emb, cate_emb, seg_emb, h32, hbf);
  for (int l = 0; l < 4; l++) {
    // zbf = silu(h @ W1[l] + b1[l])   [8192, 2048] bf16; 256x128 tiles,
    // XCD-swizzled 1D grid of 512 blocks
    mfma_gemm<256, 128, 1, 1, unsigned short><<<512, 256, 0, stream>>>(
        hbf, W1t + (size_t)l * 2048 * 512, b1 + (size_t)l * 2048, zbf, ROWS, 2048, 512);
    // yat = (silu-att @ v) * u        [8192, 512] f32; balanced qt pairs
    attn_kernel<<<dim3(8, NHEADS, 8), 256, 0, stream>>>(
        zbf, posw + (size_t)l * 4095, yat);
    // ybf = LN1(yat)  (bf16 out only)
    ln_kernel<<<ROWS / 4, 256, 0, stream>>>(yat, nullptr, ln1w + l * 512, ln1b + l * 512,
                                            nullptr, ybf);
    // t32 = ybf @ W2[l] + b2[l]   (aliases yat; yat dead after LN1)
    mfma_gemm<64, 64, 0, 0, float><<<dim3(512 / 64, ROWS / 64), 256, 0, stream>>>(
        ybf, W2t + (size_t)l * 512 * 512, b2 + (size_t)l * 512, t32, ROWS, 512, 512);
    // h = LN2(t32 + h)  (f32 + bf16 out)
    ln_kernel<<<ROWS / 4, 256, 0, stream>>>(t32, h32, ln2w + l * 512, ln2b + l * 512,
                                            h32, hbf);
  }
  // out = LNf(h)
  ln_kernel<<<ROWS / 4, 256, 0, stream>>>(h32, nullptr, lnfw, lnfb, out, nullptr);
}